// Round 6
// baseline (305.756 us; speedup 1.0000x reference)
//
#include <hip/hip_runtime.h>
#include <stdint.h>

constexpr int Dz = 96, Hy = 160, Wx = 160;
constexpr int NVOX = Dz * Hy * Wx;

// Stage-1 footprint of a 32d x 32w x 2h block (x=53d/32, z=19w/32, y=159h/160)
constexpr int ZSPAN = 20, YSPAN = 3, XSPAN = 53;   // unpadded, i-linear LDS layout
constexpr int NL = ZSPAN * YSPAN * XSPAN;          // 3180 floats per plane
constexpr int NSLOT = (NL + 255) / 256;            // 13 load slots per thread
constexpr int LBUF = NSLOT * 256;                  // 3328 floats per buffer (tail junk ok)

typedef __attribute__((address_space(3))) float lds_f;
typedef __attribute__((address_space(1))) const void gbl_v;

__global__ __launch_bounds__(256, 4) void st_fused_kernel(
    const float* __restrict__ src,
    const float* __restrict__ flows,
    const float* __restrict__ rfp,
    float* __restrict__ out)
{
    __shared__ float raw[2][LBUF];   // 26624 B double buffer
    const int t = threadIdx.x;

    // XCD-aware bijective swizzle: 1200 blocks = 8 XCDs x 150
    const int bid = blockIdx.x;
    const int swz = (bid & 7) * 150 + (bid >> 3);
    const int bx = swz % 5;
    const int rest = swz / 5;
    const int by = rest % 3;
    const int bz = rest / 3;
    const int w0 = bx * 32, d0 = by * 32, h0 = bz * 2;
    const float rf = *rfp;

    const int Z0 = (19 * w0) >> 5;
    const int X0 = (53 * d0) >> 5;
    const int YB = (159 * h0) / 160;

    // ---- per-lane global byte offsets for the plane footprint (plane-invariant) ----
    int goffb[NSLOT];
#pragma unroll
    for (int u = 0; u < NSLOT; ++u) {
        int i = t + u * 256;
        int ic = i < NL ? i : NL - 1;          // tail lanes: clamped dup loads (LDS junk, never read)
        int r = ic / XSPAN;
        int x = ic - r * XSPAN;
        int z = r / YSPAN;
        int y = r - z * YSPAN;
        goffb[u] = ((z * Hy + y) * Wx + x) * 4;
    }
    const size_t baseoff = ((size_t)(Z0 * Hy + YB) * Wx + X0) * 4;

    // Async global -> LDS staging: linear LDS dest (wave-uniform base + lane*4),
    // footprint gather carried by the per-lane GLOBAL address.
    auto issue_loads = [&](int p, int b) {
        const char* fb = (const char*)flows + (size_t)p * NVOX * 4 + baseoff;
#pragma unroll
        for (int u = 0; u < NSLOT; ++u) {
            __builtin_amdgcn_global_load_lds(
                (gbl_v*)(fb + goffb[u]),
                (lds_f*)&raw[b][t + u * 256],
                4, 0, 0);
        }
    };

    // ---- compute-phase constants: lanes vary w (stage-1 z axis) ----
    const int wl = t & 31;
    const int w = w0 + wl;
    const float zf = (float)(19 * w) * (1.0f / 32.0f);
    const int z0i = (int)zf;
    const float fz = zf - (float)z0i;
    const int zz = z0i - Z0;                    // 0..18
    const float wz0 = 1.0f - fz, wz1 = fz;

    const int dbase = t >> 5;                   // 0..7
    int xx[4]; float wx0[4], wx1[4];
#pragma unroll
    for (int k = 0; k < 4; ++k) {
        const int d = d0 + dbase + 8 * k;
        const float xf = (float)(53 * d) * (1.0f / 32.0f);
        const int x0i = (int)xf;
        const float fx = xf - (float)x0i;
        xx[k] = x0i - X0;                       // 0..51
        wx0[k] = 1.0f - fx; wx1[k] = fx;
    }

    float wyr[2][3];
#pragma unroll
    for (int j = 0; j < 2; ++j) {
        const int h = h0 + j;
        const float yf = (float)h * (159.0f / 160.0f);
        const int y0i = (int)yf;
        const float fy = yf - (float)y0i;
        const int yrel = y0i - YB;              // 0 or 1
        const float a = 1.0f - fy, b = fy;
        wyr[j][0] = (yrel == 0) ? a : 0.0f;
        wyr[j][1] = (yrel == 0) ? b : a;
        wyr[j][2] = (yrel == 0) ? 0.0f : b;
    }

    auto compute = [&](const float* lb, float (&v)[4][2]) {
        const float* zrow = lb + zz * (YSPAN * XSPAN);   // stride 159 ≡ -1 (mod 32): conflict-free
#pragma unroll
        for (int k = 0; k < 4; ++k) {
            float zv0[3], zv1[3];
#pragma unroll
            for (int yy = 0; yy < 3; ++yy) {
                const float* r0 = zrow + yy * XSPAN + xx[k];
                const float a0 = r0[0], a1 = r0[1];
                const float b0 = r0[YSPAN * XSPAN], b1 = r0[YSPAN * XSPAN + 1];
                zv0[yy] = wz0 * a0 + wz1 * b0;
                zv1[yy] = wz0 * a1 + wz1 * b1;
            }
#pragma unroll
            for (int j = 0; j < 2; ++j) {
                const float yv0 = wyr[j][0] * zv0[0] + wyr[j][1] * zv0[1] + wyr[j][2] * zv0[2];
                const float yv1 = wyr[j][0] * zv1[0] + wyr[j][1] * zv1[1] + wyr[j][2] * zv1[2];
                v[k][j] = wx0[k] * yv0 + wx1[k] * yv1;
            }
        }
    };

    float accA[4][2], accB[4][2], accC[4][2];
#pragma unroll
    for (int k = 0; k < 4; ++k)
#pragma unroll
        for (int j = 0; j < 2; ++j) { accA[k][j] = 0.f; accB[k][j] = 0.f; accC[k][j] = 0.f; }

    // ---- plane pipeline: 1 barrier/plane; p+1 loads in flight under compute of p ----
    issue_loads(0, 0);
#pragma unroll
    for (int p = 0; p < 9; ++p) {
        __syncthreads();                        // vmcnt(0) drain publishes plane p
        if (p < 8) issue_loads(p + 1, (p + 1) & 1);
        float v[4][2];
        compute(&raw[p & 1][0], v);
        const int c = p % 3;                    // static (p unrolled)
        if (c == 0) {
#pragma unroll
            for (int k = 0; k < 4; ++k) { accA[k][0] += v[k][0]; accA[k][1] += v[k][1]; }
        } else if (c == 1) {
#pragma unroll
            for (int k = 0; k < 4; ++k) { accB[k][0] += v[k][0]; accB[k][1] += v[k][1]; }
        } else {
#pragma unroll
            for (int k = 0; k < 4; ++k) { accC[k][0] += v[k][0]; accC[k][1] += v[k][1]; }
        }
    }

    // ---- stage 2: sample src (zeros mode), lanes vary w -> coalesced store ----
#pragma unroll
    for (int j = 0; j < 2; ++j) {
        const int h = h0 + j;
#pragma unroll
        for (int k = 0; k < 4; ++k) {
            const int d = d0 + dbase + 8 * k;
            const float f0 = (float)d + accA[k][j] * rf;   // -> x axis of src
            const float f1 = (float)h + accB[k][j] * rf;   // -> y axis
            const float f2 = (float)w + accC[k][j] * rf;   // -> z axis

            const float xs = f0 * (159.0f / 95.0f);
            const float ys = f1;
            const float zs = f2 * (95.0f / 159.0f);

            const float xs0f = floorf(xs), ys0f = floorf(ys), zs0f = floorf(zs);
            const float gx = xs - xs0f, gy = ys - ys0f, gz = zs - zs0f;
            const int xi0 = (int)xs0f, yi0 = (int)ys0f, zi0 = (int)zs0f;
            const int xi1 = xi0 + 1, yi1 = yi0 + 1, zi1 = zi0 + 1;

            auto samp = [&](int zi, int yi, int xi, float wt) -> float {
                bool valid = ((unsigned)zi < (unsigned)Dz)
                           & ((unsigned)yi < (unsigned)Hy)
                           & ((unsigned)xi < (unsigned)Wx);
                int zc = min(max(zi, 0), Dz - 1);
                int yc = min(max(yi, 0), Hy - 1);
                int xc = min(max(xi, 0), Wx - 1);
                float v = src[(zc * Hy + yc) * Wx + xc];
                return valid ? wt * v : 0.0f;
            };

            float r = samp(zi0, yi0, xi0, (1.0f - gz) * (1.0f - gy) * (1.0f - gx))
                    + samp(zi0, yi0, xi1, (1.0f - gz) * (1.0f - gy) * gx)
                    + samp(zi0, yi1, xi0, (1.0f - gz) * gy * (1.0f - gx))
                    + samp(zi0, yi1, xi1, (1.0f - gz) * gy * gx)
                    + samp(zi1, yi0, xi0, gz * (1.0f - gy) * (1.0f - gx))
                    + samp(zi1, yi0, xi1, gz * (1.0f - gy) * gx)
                    + samp(zi1, yi1, xi0, gz * gy * (1.0f - gx))
                    + samp(zi1, yi1, xi1, gz * gy * gx);

            out[(d * Hy + h) * Wx + w] = r;
        }
    }
}

extern "C" void kernel_launch(void* const* d_in, const int* in_sizes, int n_in,
                              void* d_out, int out_size, void* d_ws, size_t ws_size,
                              hipStream_t stream) {
    const float* src   = (const float*)d_in[0];
    const float* flows = (const float*)d_in[1];
    const float* rfp   = (const float*)d_in[2];
    float* out = (float*)d_out;

    st_fused_kernel<<<dim3(1200), 256, 0, stream>>>(src, flows, rfp, out);
}

// Round 7
// 54.721 us; speedup vs baseline: 5.5875x; 5.5875x over previous
//
#include <hip/hip_runtime.h>
#include <stdint.h>

constexpr int Dz = 96, Hy = 160, Wx = 160;
constexpr int NVOX = Dz * Hy * Wx;

// Stage-1 footprint of a 32d x 32w x 2h block (x=53d/32, z=19w/32, y=159h/160)
constexpr int ZSPAN = 20, YSPAN = 3, XSPAN = 53;   // unpadded, i-linear LDS layout
constexpr int NL = ZSPAN * YSPAN * XSPAN;          // 3180 floats per plane
constexpr int NSLOT = (NL + 255) / 256;            // 13 load slots per thread
constexpr int LBUF = NSLOT * 256;                  // 3328 floats per buffer (tail junk ok)

typedef __attribute__((address_space(3))) float lds_f;
typedef __attribute__((address_space(1))) const void gbl_v;

__global__ __launch_bounds__(256) void st_fused_kernel(
    const float* __restrict__ src,
    const float* __restrict__ flows,
    const float* __restrict__ rfp,
    float* __restrict__ out)
{
    __shared__ float raw[2][LBUF];   // 26624 B double buffer
    const int t = threadIdx.x;

    // XCD-aware bijective swizzle: 1200 blocks = 8 XCDs x 150
    const int bid = blockIdx.x;
    const int swz = (bid & 7) * 150 + (bid >> 3);
    const int bx = swz % 5;
    const int rest = swz / 5;
    const int by = rest % 3;
    const int bz = rest / 3;
    const int w0 = bx * 32, d0 = by * 32, h0 = bz * 2;
    const float rf = *rfp;

    const int Z0 = (19 * w0) >> 5;
    const int X0 = (53 * d0) >> 5;
    const int YB = (159 * h0) / 160;

    // ---- 13 live 64-bit load addresses, incremented by plane stride.
    // Fixed 26-VGPR cost; sequential dep prevents per-plane hoisting.
    const char* ap[NSLOT];
    {
        const char* fb = (const char*)flows + ((size_t)(Z0 * Hy + YB) * Wx + X0) * 4;
#pragma unroll
        for (int u = 0; u < NSLOT; ++u) {
            int i = t + u * 256;
            int ic = i < NL ? i : NL - 1;      // tail lanes: clamped dup loads (LDS junk, never read)
            int r = ic / XSPAN;
            int x = ic - r * XSPAN;
            int z = r / YSPAN;
            int y = r - z * YSPAN;
            ap[u] = fb + ((z * Hy + y) * Wx + x) * 4;
        }
    }

    auto issue_loads = [&](float* lb) {
#pragma unroll
        for (int u = 0; u < NSLOT; ++u) {
            __builtin_amdgcn_global_load_lds(
                (gbl_v*)ap[u], (lds_f*)&lb[t + u * 256], 4, 0, 0);
        }
    };
    auto advance = [&]() {
#pragma unroll
        for (int u = 0; u < NSLOT; ++u) ap[u] += (size_t)NVOX * 4;
    };

    // ---- compute-phase constants: lanes vary w (stage-1 z axis) ----
    const int wl = t & 31;
    const int w = w0 + wl;
    const float zf = (float)(19 * w) * (1.0f / 32.0f);
    const int z0i = (int)zf;
    const float fz = zf - (float)z0i;
    const int zz = z0i - Z0;                    // 0..18
    const float wz0 = 1.0f - fz, wz1 = fz;

    const int dbase = t >> 5;                   // 0..7
    int xx[4]; float wx0[4], wx1[4];
#pragma unroll
    for (int k = 0; k < 4; ++k) {
        const int d = d0 + dbase + 8 * k;
        const float xf = (float)(53 * d) * (1.0f / 32.0f);
        const int x0i = (int)xf;
        const float fx = xf - (float)x0i;
        xx[k] = x0i - X0;                       // 0..51
        wx0[k] = 1.0f - fx; wx1[k] = fx;
    }

    float wyr[2][3];
#pragma unroll
    for (int j = 0; j < 2; ++j) {
        const int h = h0 + j;
        const float yf = (float)h * (159.0f / 160.0f);
        const int y0i = (int)yf;
        const float fy = yf - (float)y0i;
        const int yrel = y0i - YB;              // 0 or 1
        const float a = 1.0f - fy, b = fy;
        wyr[j][0] = (yrel == 0) ? a : 0.0f;
        wyr[j][1] = (yrel == 0) ? b : a;
        wyr[j][2] = (yrel == 0) ? 0.0f : b;
    }

    auto compute = [&](const float* lb, float (&v)[4][2]) {
        const float* zrow = lb + zz * (YSPAN * XSPAN);   // stride 159 ≡ -1 (mod 32): conflict-free
#pragma unroll
        for (int k = 0; k < 4; ++k) {
            float zv0[3], zv1[3];
#pragma unroll
            for (int yy = 0; yy < 3; ++yy) {
                const float* r0 = zrow + yy * XSPAN + xx[k];
                const float a0 = r0[0], a1 = r0[1];
                const float b0 = r0[YSPAN * XSPAN], b1 = r0[YSPAN * XSPAN + 1];
                zv0[yy] = wz0 * a0 + wz1 * b0;
                zv1[yy] = wz0 * a1 + wz1 * b1;
            }
#pragma unroll
            for (int j = 0; j < 2; ++j) {
                const float yv0 = wyr[j][0] * zv0[0] + wyr[j][1] * zv0[1] + wyr[j][2] * zv0[2];
                const float yv1 = wyr[j][0] * zv1[0] + wyr[j][1] * zv1[1] + wyr[j][2] * zv1[2];
                v[k][j] = wx0[k] * yv0 + wx1[k] * yv1;
            }
        }
    };

    float accA[4][2], accB[4][2], accC[4][2];
#pragma unroll
    for (int k = 0; k < 4; ++k)
#pragma unroll
        for (int j = 0; j < 2; ++j) { accA[k][j] = 0.f; accB[k][j] = 0.f; accC[k][j] = 0.f; }

    // ---- rolled plane pipeline: 3 outer iters x 3 static planes, dbuf via ptr swap ----
    float* cur = &raw[0][0];
    float* nxt = &raw[1][0];

    issue_loads(cur);      // plane 0
    advance();
#pragma unroll 1
    for (int i = 0; i < 3; ++i) {
        // plane 3i -> channel A
        __syncthreads();
        issue_loads(nxt);                  // plane 3i+1
        advance();
        {
            float v[4][2]; compute(cur, v);
#pragma unroll
            for (int k = 0; k < 4; ++k) { accA[k][0] += v[k][0]; accA[k][1] += v[k][1]; }
        }
        { float* tmp = cur; cur = nxt; nxt = tmp; }

        // plane 3i+1 -> channel B
        __syncthreads();
        issue_loads(nxt);                  // plane 3i+2
        advance();
        {
            float v[4][2]; compute(cur, v);
#pragma unroll
            for (int k = 0; k < 4; ++k) { accB[k][0] += v[k][0]; accB[k][1] += v[k][1]; }
        }
        { float* tmp = cur; cur = nxt; nxt = tmp; }

        // plane 3i+2 -> channel C
        __syncthreads();
        if (i < 2) {
            issue_loads(nxt);              // plane 3i+3
            advance();
        }
        {
            float v[4][2]; compute(cur, v);
#pragma unroll
            for (int k = 0; k < 4; ++k) { accC[k][0] += v[k][0]; accC[k][1] += v[k][1]; }
        }
        { float* tmp = cur; cur = nxt; nxt = tmp; }
    }

    // ---- stage 2: sample src (zeros mode), lanes vary w -> coalesced store ----
#pragma unroll
    for (int j = 0; j < 2; ++j) {
        const int h = h0 + j;
#pragma unroll
        for (int k = 0; k < 4; ++k) {
            const int d = d0 + dbase + 8 * k;
            const float f0 = (float)d + accA[k][j] * rf;   // -> x axis of src
            const float f1 = (float)h + accB[k][j] * rf;   // -> y axis
            const float f2 = (float)w + accC[k][j] * rf;   // -> z axis

            const float xs = f0 * (159.0f / 95.0f);
            const float ys = f1;
            const float zs = f2 * (95.0f / 159.0f);

            const float xs0f = floorf(xs), ys0f = floorf(ys), zs0f = floorf(zs);
            const float gx = xs - xs0f, gy = ys - ys0f, gz = zs - zs0f;
            const int xi0 = (int)xs0f, yi0 = (int)ys0f, zi0 = (int)zs0f;
            const int xi1 = xi0 + 1, yi1 = yi0 + 1, zi1 = zi0 + 1;

            auto samp = [&](int zi, int yi, int xi, float wt) -> float {
                bool valid = ((unsigned)zi < (unsigned)Dz)
                           & ((unsigned)yi < (unsigned)Hy)
                           & ((unsigned)xi < (unsigned)Wx);
                int zc = min(max(zi, 0), Dz - 1);
                int yc = min(max(yi, 0), Hy - 1);
                int xc = min(max(xi, 0), Wx - 1);
                float v = src[(zc * Hy + yc) * Wx + xc];
                return valid ? wt * v : 0.0f;
            };

            float r = samp(zi0, yi0, xi0, (1.0f - gz) * (1.0f - gy) * (1.0f - gx))
                    + samp(zi0, yi0, xi1, (1.0f - gz) * (1.0f - gy) * gx)
                    + samp(zi0, yi1, xi0, (1.0f - gz) * gy * (1.0f - gx))
                    + samp(zi0, yi1, xi1, (1.0f - gz) * gy * gx)
                    + samp(zi1, yi0, xi0, gz * (1.0f - gy) * (1.0f - gx))
                    + samp(zi1, yi0, xi1, gz * (1.0f - gy) * gx)
                    + samp(zi1, yi1, xi0, gz * gy * (1.0f - gx))
                    + samp(zi1, yi1, xi1, gz * gy * gx);

            out[(d * Hy + h) * Wx + w] = r;
        }
    }
}

extern "C" void kernel_launch(void* const* d_in, const int* in_sizes, int n_in,
                              void* d_out, int out_size, void* d_ws, size_t ws_size,
                              hipStream_t stream) {
    const float* src   = (const float*)d_in[0];
    const float* flows = (const float*)d_in[1];
    const float* rfp   = (const float*)d_in[2];
    float* out = (float*)d_out;

    st_fused_kernel<<<dim3(1200), 256, 0, stream>>>(src, flows, rfp, out);
}